// Round 10
// baseline (166.494 us; speedup 1.0000x reference)
//
#include <hip/hip_runtime.h>
#include <math.h>

#define N_ANT 64
#define BATCH 131072
#define NSTEPS 63      // 31 internal softmax units + 32 leaf groups, DFS preorder
#define TPB 1024       // 16 waves; wave w owns m-tile w (weight cols 16w..16w+15)
#define NBLK 512       // 512 blocks x 256 elems; 2 blocks/CU co-resident
#define EPR 64         // elems per round
#define ROUNDS 4       // 256 elems per block
#define PSTRH 126      // p-buffer ELEM-major row stride in HALVES: 63*2, no pad
                       // (126 halves = 63 dwords, odd -> banks spread (u-er)%32)

typedef float f32x4 __attribute__((ext_vector_type(4)));
typedef float v2f   __attribute__((ext_vector_type(2)));
typedef _Float16 f16x8 __attribute__((ext_vector_type(8)));
typedef _Float16 f16x2 __attribute__((ext_vector_type(2)));

// Workgroup barrier WITHOUT the vmcnt(0) drain __syncthreads() forces.
// Cross-wave ordering here only ever communicates through LDS (xb staging,
// pb softmax pairs) -> draining lgkmcnt before s_barrier is sufficient.
#define BAR_LGKM() asm volatile("s_waitcnt lgkmcnt(0)\n\ts_barrier" ::: "memory")

static __device__ __forceinline__ float fast_rcp(float x) {
#if __has_builtin(__builtin_amdgcn_rcpf)
    return __builtin_amdgcn_rcpf(x);
#else
    return 1.0f / x;
#endif
}

// Advance DFS-preorder state over the complete binary tree.
// Internal units: l=0..4 (node n at layer l). Leaf groups: l==5 (group n).
static __device__ __forceinline__ void dfs_next(int& l, int& n) {
    if (l < 5) { l = l + 1; n = 2 * n; }
    else {
        while (n & 1) { n >>= 1; l--; }
        n += 1;
    }
}

// Build W operand (252 M x 128 K real, M 252..255 zero-padded) as a SINGLE
// round-to-nearest fp16 image, prepacked in MFMA A-fragment order:
//   slot t = ((mtile*4 + kstep)*64 + lane), 8 contiguous fp16 per slot,
//   element j -> W[m = mtile*16 + (lane&15)][k = kstep*32 + (lane>>4)*8 + j].
// Real row m=2c -> [wr ; -wi] over k, m=2c+1 -> [wi ; wr]; unit s = c>>1 DFS.
__global__ void fill_B(const float* __restrict__ t0, const float* __restrict__ t1,
                       const float* __restrict__ t2, const float* __restrict__ t3,
                       const float* __restrict__ t4,
                       _Float16* __restrict__ B1p) {
    const int t = blockIdx.x * 256 + threadIdx.x;   // 0..4095
    const int L = t & 63;
    const int kstep = (t >> 6) & 3;
    const int ntile = t >> 8;
    const int n = ntile * 16 + (L & 15);
    const int kbase = kstep * 32 + (L >> 4) * 8;

    f16x8 h1 = {0,0,0,0,0,0,0,0};
    if (n < 252) {
        const int c = n >> 1, part = n & 1;
        const int s = c >> 1, kidx = c & 1;
        int l = 0, nn = 0;
        for (int i = 0; i < s; ++i) dfs_next(l, nn);

        // Leaf-only per-thread constant: cosaz for this beam column.
        const double step = (-2.0 + 5e-13) / 63.0;   // (cos(pi-1e-6)-1)/63
        const double cosaz = 1.0 + (double)(2 * nn + kidx) * step;

#pragma unroll
        for (int j = 0; j < 8; ++j) {
            const int k = kbase + j;
            const int a = k & 63;       // antenna
            const int hi = k >> 6;      // 0: real-part rows, 1: imag-part rows
            float wr, wi;
            if (l < 5) {
                const float* th = (l == 0) ? t0 : (l == 1) ? t1 : (l == 2) ? t2
                                 : (l == 3) ? t3 : t4;
                float theta = th[(nn * N_ANT + a) * 2 + kidx];
                float sn, cs;
                sincosf(theta, &sn, &cs);
                wr = cs * 0.125f; wi = sn * 0.125f;
            } else {
                // W = exp(i*pi*a*cosaz)/8. Reduce phase/(2pi) in f64 (FMA
                // only), then f32 sincos of 2*pi*frac — no f64 libm.
                double tph = (double)a * cosaz * 0.5;
                tph -= floor(tph);                    // [0,1)
                const float ang = (float)tph * 6.283185307179586f;
                float sn, cs;
                sincosf(ang, &sn, &cs);
                wr = cs * 0.125f;
                wi = sn * 0.125f;
            }
            float v = (part == 0) ? (hi == 0 ? wr : -wi)
                                  : (hi == 0 ? wi :  wr);
            h1[j] = (_Float16)v;    // round-to-nearest fp16
        }
    }
    *(f16x8*)(B1p + (size_t)t * 8) = h1;
}

__global__ __launch_bounds__(TPB, 8) void beam_mfma(const float* __restrict__ x,
                                                    const _Float16* __restrict__ W1p,
                                                    float* __restrict__ out) {
    // x slice (64 elems x 128) as fp16, frag-swizzled, double-buffered (32 KB).
    __shared__ _Float16 xb[2][8192];
    // softmax pairs in FP16, ELEM-major [64 elems][PSTRH], dbuf (31.5 KB).
    __shared__ _Float16 pb[2][EPR * PSTRH];

    const int tid = threadIdx.x;
    const int w   = tid >> 6;     // wave = m-tile (units 4w..4w+3)
    const int L   = tid & 63;
    const int q   = L >> 4;
    const int e15 = L & 15;

    // ---- W fragments (A-operand) for m-tile w, single fp16 image.
    f16x8 w1f[4];
#pragma unroll
    for (int ks = 0; ks < 4; ++ks)
        w1f[ks] = *(const f16x8*)(W1p + (size_t)((w * 4 + ks) * 64 + L) * 8);

    // ---- Per-lane DFS metadata: lane u == DFS unit u in the tree phase.
    int myl = -1, myn = 0;
    {
        int cl = 0, cn = 0;
        for (int s = 0; s < NSTEPS; ++s) {
            if (s == L) { myl = cl; myn = cn; }
            dfs_next(cl, cn);
        }
    }
    // Leaf lane: DFS indices of its 5 internal ancestors + branch sides.
    const int sd0 = (myn >> 4) & 1, sd1 = (myn >> 3) & 1, sd2 = (myn >> 2) & 1,
              sd3 = (myn >> 1) & 1, sd4 = myn & 1;
    const int a0 = 0;
    const int a1 = a0 + 1 + sd0 * 31;   // subtree sizes 31,15,7,3
    const int a2 = a1 + 1 + sd1 * 15;
    const int a3 = a2 + 1 + sd2 * 7;
    const int a4 = a3 + 1 + sd3 * 3;

    // ---- Staging decode: thread handles 8 floats (one fragment slot) of
    // the round's 64x128 x slice. er fastest -> conflict-free LDS writes.
    const int s_er = tid & 63;
    const int s_rt = tid >> 6;            // 0..15 = ks*4 + q
    const int s_ks = s_rt >> 2;
    const int s_q  = s_rt & 3;
    const int s_goff = s_er * 128 + s_ks * 32 + s_q * 8;    // floats
    const int s_loff = (s_rt * 64 + s_er) * 8;              // halves

    const long base = (long)blockIdx.x * (EPR * ROUNDS);

    // Tree cascade for round rr using buffer bb (wave-private, 4 elems).
    auto tree_pass = [&](int bb, int rr) {
#pragma unroll
        for (int pass = 0; pass < 4; ++pass) {
            const int er = 4 * w + pass;
            const _Float16* prow = &pb[bb][er * PSTRH];
            if (myl == 5) {
                f16x2 ownh = *(const f16x2*)(prow + 2 * L);
                f16x2 q0 = *(const f16x2*)(prow + 2 * a0);
                f16x2 q1 = *(const f16x2*)(prow + 2 * a1);
                f16x2 q2 = *(const f16x2*)(prow + 2 * a2);
                f16x2 q3 = *(const f16x2*)(prow + 2 * a3);
                f16x2 q4 = *(const f16x2*)(prow + 2 * a4);
                float P = (float)(sd0 ? q0.y : q0.x) * (float)(sd1 ? q1.y : q1.x)
                        * (float)(sd2 ? q2.y : q2.x) * (float)(sd3 ? q3.y : q3.x)
                        * (float)(sd4 ? q4.y : q4.x);
                *(v2f*)(out + (base + (long)rr * EPR + er) * 64 + 2 * myn) =
                    (v2f){P * (float)ownh.x, P * (float)ownh.y};
            }
        }
    };

    // Prologue: stage slice 0; pre-load slice 1 into registers.
    {
        float4 va = *(const float4*)(x + base * 128 + s_goff);
        float4 vb = *(const float4*)(x + base * 128 + s_goff + 4);
        f16x8 hv = {(_Float16)va.x, (_Float16)va.y, (_Float16)va.z, (_Float16)va.w,
                    (_Float16)vb.x, (_Float16)vb.y, (_Float16)vb.z, (_Float16)vb.w};
        *(f16x8*)(&xb[0][s_loff]) = hv;
    }
    float4 nva = {0.f,0.f,0.f,0.f}, nvb = {0.f,0.f,0.f,0.f};
    if (ROUNDS > 1) {
        nva = *(const float4*)(x + (base + EPR) * 128 + s_goff);
        nvb = *(const float4*)(x + (base + EPR) * 128 + s_goff + 4);
    }
    BAR_LGKM();

#pragma unroll 1
    for (int r = 0; r < ROUNDS; ++r) {
        const int cur = r & 1;
        // Issue the r+2 load now: a full round between issue and use.
        float4 nv2a = {0.f,0.f,0.f,0.f}, nv2b = {0.f,0.f,0.f,0.f};
        if (r + 2 < ROUNDS) {
            nv2a = *(const float4*)(x + (base + (long)(r + 2) * EPR) * 128 + s_goff);
            nv2b = *(const float4*)(x + (base + (long)(r + 2) * EPR) * 128 + s_goff + 4);
        }

        // ---- MFMA: 4 independent chains (4 elem-groups of 16).
        f32x4 acc0 = {0,0,0,0}, acc1 = {0,0,0,0};
        f32x4 acc2 = {0,0,0,0}, acc3 = {0,0,0,0};
#pragma unroll
        for (int ks = 0; ks < 4; ++ks) {
            const _Float16* xc = &xb[cur][(size_t)((ks * 4 + q) * 64) * 8];
            f16x8 b0 = *(const f16x8*)(xc + e15 * 8);
            f16x8 b1 = *(const f16x8*)(xc + (16 + e15) * 8);
            f16x8 b2 = *(const f16x8*)(xc + (32 + e15) * 8);
            f16x8 b3 = *(const f16x8*)(xc + (48 + e15) * 8);
            acc0 = __builtin_amdgcn_mfma_f32_16x16x32_f16(w1f[ks], b0, acc0, 0, 0, 0);
            acc1 = __builtin_amdgcn_mfma_f32_16x16x32_f16(w1f[ks], b1, acc1, 0, 0, 0);
            acc2 = __builtin_amdgcn_mfma_f32_16x16x32_f16(w1f[ks], b2, acc2, 0, 0, 0);
            acc3 = __builtin_amdgcn_mfma_f32_16x16x32_f16(w1f[ks], b3, acc3, 0, 0, 0);
        }

        // ---- Tree for the PREVIOUS round, hidden under the MFMA phase
        // (reads pb[cur^1]; softmax below writes pb[cur] — disjoint).
        if (r > 0) tree_pass(cur ^ 1, r - 1);

        // ---- Lane-local softmax: lane holds (re0,im0,re1,im1) of unit u,
        // elem er = g*16+e15. fp16 pair store; elem-major spreads banks.
        const int u = 4 * w + q;
#pragma unroll
        for (int g = 0; g < 4; ++g) {
            f32x4 a = (g == 0) ? acc0 : (g == 1) ? acc1 : (g == 2) ? acc2 : acc3;
            float g0 = fmaf(a.x, a.x, a.y * a.y);
            float g1 = fmaf(a.z, a.z, a.w * a.w);
            float m  = fmaxf(g0, g1);
            float e0 = __expf(g0 - m);
            float e1 = __expf(g1 - m);
            float inv = fast_rcp(e0 + e1);
            if (u < NSTEPS)   // u==63 = zero-padded cols, must not write
                *(f16x2*)(&pb[cur][(g * 16 + e15) * PSTRH + 2 * u]) =
                    (f16x2){(_Float16)(e0 * inv), (_Float16)(e1 * inv)};
        }

        // ---- Stage slice r+1 (loaded a full round ago -> latency hidden).
        if (r + 1 < ROUNDS) {
            f16x8 hv = {(_Float16)nva.x, (_Float16)nva.y, (_Float16)nva.z, (_Float16)nva.w,
                        (_Float16)nvb.x, (_Float16)nvb.y, (_Float16)nvb.z, (_Float16)nvb.w};
            *(f16x8*)(&xb[cur ^ 1][s_loff]) = hv;
        }
        nva = nv2a; nvb = nv2b;

        BAR_LGKM();   // LDS visibility only; no vmcnt drain of stores/prefetch
    }

    // Epilogue: tree for the final round.
    tree_pass((ROUNDS - 1) & 1, ROUNDS - 1);
}

extern "C" void kernel_launch(void* const* d_in, const int* in_sizes, int n_in,
                              void* d_out, int out_size, void* d_ws, size_t ws_size,
                              hipStream_t stream) {
    const float* x  = (const float*)d_in[0];
    const float* t0 = (const float*)d_in[1];
    const float* t1 = (const float*)d_in[2];
    const float* t2 = (const float*)d_in[3];
    const float* t3 = (const float*)d_in[4];
    const float* t4 = (const float*)d_in[5];
    _Float16* W1p = (_Float16*)d_ws;                      // 64 KB

    fill_B<<<dim3(16), dim3(256), 0, stream>>>(t0, t1, t2, t3, t4, W1p);
    beam_mfma<<<dim3(NBLK), dim3(TPB), 0, stream>>>(x, W1p, (float*)d_out);
}

// Round 11
// 134.182 us; speedup vs baseline: 1.2408x; 1.2408x over previous
//
#include <hip/hip_runtime.h>
#include <math.h>

#define N_ANT 64
#define BATCH 131072
#define NSTEPS 63      // 31 internal softmax units + 32 leaf groups, DFS preorder
#define TPB 1024       // 16 waves; wave w owns m-tile w (weight cols 16w..16w+15)
#define NBLK 512       // 512 blocks x 256 elems; 2 blocks/CU co-resident (LDS 65KB)
#define EPR 64         // elems per round
#define ROUNDS 4       // 256 elems per block
#define PSTRH 126      // p-buffer ELEM-major row stride in HALVES: 63*2, no pad
                       // (126 halves = 63 dwords, odd -> banks spread (u-er)%32)

typedef float f32x4 __attribute__((ext_vector_type(4)));
typedef float v2f   __attribute__((ext_vector_type(2)));
typedef _Float16 f16x8 __attribute__((ext_vector_type(8)));
typedef _Float16 f16x2 __attribute__((ext_vector_type(2)));

// Workgroup barrier WITHOUT the vmcnt(0) drain __syncthreads() forces.
// Cross-wave ordering here only ever communicates through LDS (xb staging,
// pb softmax pairs) -> draining lgkmcnt before s_barrier is sufficient.
#define BAR_LGKM() asm volatile("s_waitcnt lgkmcnt(0)\n\ts_barrier" ::: "memory")

static __device__ __forceinline__ float fast_rcp(float x) {
#if __has_builtin(__builtin_amdgcn_rcpf)
    return __builtin_amdgcn_rcpf(x);
#else
    return 1.0f / x;
#endif
}

// Advance DFS-preorder state over the complete binary tree.
// Internal units: l=0..4 (node n at layer l). Leaf groups: l==5 (group n).
static __device__ __forceinline__ void dfs_next(int& l, int& n) {
    if (l < 5) { l = l + 1; n = 2 * n; }
    else {
        while (n & 1) { n >>= 1; l--; }
        n += 1;
    }
}

// Build W operand (252 M x 128 K real, M 252..255 zero-padded) as a SINGLE
// round-to-nearest fp16 image, prepacked in MFMA A-fragment order:
//   slot t = ((mtile*4 + kstep)*64 + lane), 8 contiguous fp16 per slot,
//   element j -> W[m = mtile*16 + (lane&15)][k = kstep*32 + (lane>>4)*8 + j].
// Real row m=2c -> [wr ; -wi] over k, m=2c+1 -> [wi ; wr]; unit s = c>>1 DFS.
__global__ void fill_B(const float* __restrict__ t0, const float* __restrict__ t1,
                       const float* __restrict__ t2, const float* __restrict__ t3,
                       const float* __restrict__ t4,
                       _Float16* __restrict__ B1p) {
    const int t = blockIdx.x * 256 + threadIdx.x;   // 0..4095
    const int L = t & 63;
    const int kstep = (t >> 6) & 3;
    const int ntile = t >> 8;
    const int n = ntile * 16 + (L & 15);
    const int kbase = kstep * 32 + (L >> 4) * 8;

    f16x8 h1 = {0,0,0,0,0,0,0,0};
    if (n < 252) {
        const int c = n >> 1, part = n & 1;
        const int s = c >> 1, kidx = c & 1;
        int l = 0, nn = 0;
        for (int i = 0; i < s; ++i) dfs_next(l, nn);

        // Leaf-only per-thread constant: cosaz for this beam column.
        const double step = (-2.0 + 5e-13) / 63.0;   // (cos(pi-1e-6)-1)/63
        const double cosaz = 1.0 + (double)(2 * nn + kidx) * step;

#pragma unroll
        for (int j = 0; j < 8; ++j) {
            const int k = kbase + j;
            const int a = k & 63;       // antenna
            const int hi = k >> 6;      // 0: real-part rows, 1: imag-part rows
            float wr, wi;
            if (l < 5) {
                const float* th = (l == 0) ? t0 : (l == 1) ? t1 : (l == 2) ? t2
                                 : (l == 3) ? t3 : t4;
                float theta = th[(nn * N_ANT + a) * 2 + kidx];
                float sn, cs;
                sincosf(theta, &sn, &cs);
                wr = cs * 0.125f; wi = sn * 0.125f;
            } else {
                // W = exp(i*pi*a*cosaz)/8. Reduce phase/(2pi) in f64 (FMA
                // only), then f32 sincos of 2*pi*frac — no f64 libm.
                double tph = (double)a * cosaz * 0.5;
                tph -= floor(tph);                    // [0,1)
                const float ang = (float)tph * 6.283185307179586f;
                float sn, cs;
                sincosf(ang, &sn, &cs);
                wr = cs * 0.125f;
                wi = sn * 0.125f;
            }
            float v = (part == 0) ? (hi == 0 ? wr : -wi)
                                  : (hi == 0 ? wi :  wr);
            h1[j] = (_Float16)v;    // round-to-nearest fp16
        }
    }
    *(f16x8*)(B1p + (size_t)t * 8) = h1;
}

// NO min-waves hint: the allocator naturally lands at ~44 VGPR (round 9),
// which is <= the 64-VGPR cap for 8 waves/EU, so 2 blocks/CU schedule
// without spills. __launch_bounds__(TPB, 8) forced VGPR 32 + scratch
// spills (+150 MB HBM traffic) in round 10 — do not reintroduce it.
__global__ __launch_bounds__(TPB) void beam_mfma(const float* __restrict__ x,
                                                 const _Float16* __restrict__ W1p,
                                                 float* __restrict__ out) {
    // x slice (64 elems x 128) as fp16, frag-swizzled, double-buffered (32 KB).
    __shared__ _Float16 xb[2][8192];
    // softmax pairs in FP16, ELEM-major [64 elems][PSTRH], dbuf (31.5 KB).
    __shared__ _Float16 pb[2][EPR * PSTRH];

    const int tid = threadIdx.x;
    const int w   = tid >> 6;     // wave = m-tile (units 4w..4w+3)
    const int L   = tid & 63;
    const int q   = L >> 4;
    const int e15 = L & 15;

    // ---- W fragments (A-operand) for m-tile w, single fp16 image.
    f16x8 w1f[4];
#pragma unroll
    for (int ks = 0; ks < 4; ++ks)
        w1f[ks] = *(const f16x8*)(W1p + (size_t)((w * 4 + ks) * 64 + L) * 8);

    // ---- Per-lane DFS metadata: lane u == DFS unit u in the tree phase.
    int myl = -1, myn = 0;
    {
        int cl = 0, cn = 0;
        for (int s = 0; s < NSTEPS; ++s) {
            if (s == L) { myl = cl; myn = cn; }
            dfs_next(cl, cn);
        }
    }
    // Leaf lane: DFS indices of its 5 internal ancestors + branch sides.
    const int sd0 = (myn >> 4) & 1, sd1 = (myn >> 3) & 1, sd2 = (myn >> 2) & 1,
              sd3 = (myn >> 1) & 1, sd4 = myn & 1;
    const int a0 = 0;
    const int a1 = a0 + 1 + sd0 * 31;   // subtree sizes 31,15,7,3
    const int a2 = a1 + 1 + sd1 * 15;
    const int a3 = a2 + 1 + sd2 * 7;
    const int a4 = a3 + 1 + sd3 * 3;

    // ---- Staging decode: thread handles 8 floats (one fragment slot) of
    // the round's 64x128 x slice. er fastest -> conflict-free LDS writes.
    const int s_er = tid & 63;
    const int s_rt = tid >> 6;            // 0..15 = ks*4 + q
    const int s_ks = s_rt >> 2;
    const int s_q  = s_rt & 3;
    const int s_goff = s_er * 128 + s_ks * 32 + s_q * 8;    // floats
    const int s_loff = (s_rt * 64 + s_er) * 8;              // halves

    const long base = (long)blockIdx.x * (EPR * ROUNDS);

    // Tree cascade for round rr using buffer bb (wave-private, 4 elems).
    auto tree_pass = [&](int bb, int rr) {
#pragma unroll
        for (int pass = 0; pass < 4; ++pass) {
            const int er = 4 * w + pass;
            const _Float16* prow = &pb[bb][er * PSTRH];
            if (myl == 5) {
                f16x2 ownh = *(const f16x2*)(prow + 2 * L);
                f16x2 q0 = *(const f16x2*)(prow + 2 * a0);
                f16x2 q1 = *(const f16x2*)(prow + 2 * a1);
                f16x2 q2 = *(const f16x2*)(prow + 2 * a2);
                f16x2 q3 = *(const f16x2*)(prow + 2 * a3);
                f16x2 q4 = *(const f16x2*)(prow + 2 * a4);
                float P = (float)(sd0 ? q0.y : q0.x) * (float)(sd1 ? q1.y : q1.x)
                        * (float)(sd2 ? q2.y : q2.x) * (float)(sd3 ? q3.y : q3.x)
                        * (float)(sd4 ? q4.y : q4.x);
                *(v2f*)(out + (base + (long)rr * EPR + er) * 64 + 2 * myn) =
                    (v2f){P * (float)ownh.x, P * (float)ownh.y};
            }
        }
    };

    // Prologue: stage slice 0; pre-load slice 1 into registers.
    {
        float4 va = *(const float4*)(x + base * 128 + s_goff);
        float4 vb = *(const float4*)(x + base * 128 + s_goff + 4);
        f16x8 hv = {(_Float16)va.x, (_Float16)va.y, (_Float16)va.z, (_Float16)va.w,
                    (_Float16)vb.x, (_Float16)vb.y, (_Float16)vb.z, (_Float16)vb.w};
        *(f16x8*)(&xb[0][s_loff]) = hv;
    }
    float4 nva = {0.f,0.f,0.f,0.f}, nvb = {0.f,0.f,0.f,0.f};
    if (ROUNDS > 1) {
        nva = *(const float4*)(x + (base + EPR) * 128 + s_goff);
        nvb = *(const float4*)(x + (base + EPR) * 128 + s_goff + 4);
    }
    BAR_LGKM();

#pragma unroll 1
    for (int r = 0; r < ROUNDS; ++r) {
        const int cur = r & 1;
        // Issue the r+2 load now: a full round between issue and use.
        float4 nv2a = {0.f,0.f,0.f,0.f}, nv2b = {0.f,0.f,0.f,0.f};
        if (r + 2 < ROUNDS) {
            nv2a = *(const float4*)(x + (base + (long)(r + 2) * EPR) * 128 + s_goff);
            nv2b = *(const float4*)(x + (base + (long)(r + 2) * EPR) * 128 + s_goff + 4);
        }

        // ---- MFMA: 4 independent chains (4 elem-groups of 16).
        f32x4 acc0 = {0,0,0,0}, acc1 = {0,0,0,0};
        f32x4 acc2 = {0,0,0,0}, acc3 = {0,0,0,0};
#pragma unroll
        for (int ks = 0; ks < 4; ++ks) {
            const _Float16* xc = &xb[cur][(size_t)((ks * 4 + q) * 64) * 8];
            f16x8 b0 = *(const f16x8*)(xc + e15 * 8);
            f16x8 b1 = *(const f16x8*)(xc + (16 + e15) * 8);
            f16x8 b2 = *(const f16x8*)(xc + (32 + e15) * 8);
            f16x8 b3 = *(const f16x8*)(xc + (48 + e15) * 8);
            acc0 = __builtin_amdgcn_mfma_f32_16x16x32_f16(w1f[ks], b0, acc0, 0, 0, 0);
            acc1 = __builtin_amdgcn_mfma_f32_16x16x32_f16(w1f[ks], b1, acc1, 0, 0, 0);
            acc2 = __builtin_amdgcn_mfma_f32_16x16x32_f16(w1f[ks], b2, acc2, 0, 0, 0);
            acc3 = __builtin_amdgcn_mfma_f32_16x16x32_f16(w1f[ks], b3, acc3, 0, 0, 0);
        }

        // ---- Tree for the PREVIOUS round, hidden under the MFMA phase
        // (reads pb[cur^1]; softmax below writes pb[cur] — disjoint).
        if (r > 0) tree_pass(cur ^ 1, r - 1);

        // ---- Lane-local softmax: lane holds (re0,im0,re1,im1) of unit u,
        // elem er = g*16+e15. fp16 pair store; elem-major spreads banks.
        const int u = 4 * w + q;
#pragma unroll
        for (int g = 0; g < 4; ++g) {
            f32x4 a = (g == 0) ? acc0 : (g == 1) ? acc1 : (g == 2) ? acc2 : acc3;
            float g0 = fmaf(a.x, a.x, a.y * a.y);
            float g1 = fmaf(a.z, a.z, a.w * a.w);
            float m  = fmaxf(g0, g1);
            float e0 = __expf(g0 - m);
            float e1 = __expf(g1 - m);
            float inv = fast_rcp(e0 + e1);
            if (u < NSTEPS)   // u==63 = zero-padded cols, must not write
                *(f16x2*)(&pb[cur][(g * 16 + e15) * PSTRH + 2 * u]) =
                    (f16x2){(_Float16)(e0 * inv), (_Float16)(e1 * inv)};
        }

        // ---- Stage slice r+1 (loaded a full round ago -> latency hidden).
        if (r + 1 < ROUNDS) {
            f16x8 hv = {(_Float16)nva.x, (_Float16)nva.y, (_Float16)nva.z, (_Float16)nva.w,
                        (_Float16)nvb.x, (_Float16)nvb.y, (_Float16)nvb.z, (_Float16)nvb.w};
            *(f16x8*)(&xb[cur ^ 1][s_loff]) = hv;
        }
        nva = nv2a; nvb = nv2b;

        BAR_LGKM();   // LDS visibility only; no vmcnt drain of stores/prefetch
    }

    // Epilogue: tree for the final round.
    tree_pass((ROUNDS - 1) & 1, ROUNDS - 1);
}

extern "C" void kernel_launch(void* const* d_in, const int* in_sizes, int n_in,
                              void* d_out, int out_size, void* d_ws, size_t ws_size,
                              hipStream_t stream) {
    const float* x  = (const float*)d_in[0];
    const float* t0 = (const float*)d_in[1];
    const float* t1 = (const float*)d_in[2];
    const float* t2 = (const float*)d_in[3];
    const float* t3 = (const float*)d_in[4];
    const float* t4 = (const float*)d_in[5];
    _Float16* W1p = (_Float16*)d_ws;                      // 64 KB

    fill_B<<<dim3(16), dim3(256), 0, stream>>>(t0, t1, t2, t3, t4, W1p);
    beam_mfma<<<dim3(NBLK), dim3(TPB), 0, stream>>>(x, W1p, (float*)d_out);
}

// Round 12
// 125.087 us; speedup vs baseline: 1.3310x; 1.0727x over previous
//
#include <hip/hip_runtime.h>
#include <math.h>

#define N_ANT 64
#define BATCH 131072
#define NSTEPS 63      // 31 internal softmax units + 32 leaf groups, DFS preorder
#define TPB 512        // 8 waves; wave w owns m-tiles 2w,2w+1 (units 8w..8w+7)
#define NBLK 512       // 512 blocks x 256 elems; 2 blocks/CU (32.2 KB LDS each)
#define EPR 32         // elems per round
#define ROUNDS 8       // 256 elems per block
#define PSTRH 126      // p-buffer ELEM-major row stride in HALVES: 63*2, no pad

typedef float f32x4 __attribute__((ext_vector_type(4)));
typedef float v2f   __attribute__((ext_vector_type(2)));
typedef _Float16 f16x8 __attribute__((ext_vector_type(8)));
typedef _Float16 f16x2 __attribute__((ext_vector_type(2)));

// Workgroup barrier WITHOUT the vmcnt(0) drain __syncthreads() forces.
// Cross-wave ordering only communicates through LDS (xb, pb) -> lgkmcnt
// drain before s_barrier is sufficient.
#define BAR_LGKM() asm volatile("s_waitcnt lgkmcnt(0)\n\ts_barrier" ::: "memory")

static __device__ __forceinline__ float fast_rcp(float x) {
#if __has_builtin(__builtin_amdgcn_rcpf)
    return __builtin_amdgcn_rcpf(x);
#else
    return 1.0f / x;
#endif
}

// Advance DFS-preorder state over the complete binary tree.
// Internal units: l=0..4 (node n at layer l). Leaf groups: l==5 (group n).
static __device__ __forceinline__ void dfs_next(int& l, int& n) {
    if (l < 5) { l = l + 1; n = 2 * n; }
    else {
        while (n & 1) { n >>= 1; l--; }
        n += 1;
    }
}

// Build W operand (252 M x 128 K real, M 252..255 zero-padded) as a SINGLE
// round-to-nearest fp16 image, prepacked in MFMA A-fragment order:
//   slot t = ((mtile*4 + kstep)*64 + lane), 8 contiguous fp16 per slot,
//   element j -> W[m = mtile*16 + (lane&15)][k = kstep*32 + (lane>>4)*8 + j].
// Real row m=2c -> [wr ; -wi] over k, m=2c+1 -> [wi ; wr]; unit s = c>>1 DFS.
__global__ void fill_B(const float* __restrict__ t0, const float* __restrict__ t1,
                       const float* __restrict__ t2, const float* __restrict__ t3,
                       const float* __restrict__ t4,
                       _Float16* __restrict__ B1p) {
    const int t = blockIdx.x * 256 + threadIdx.x;   // 0..4095
    const int L = t & 63;
    const int kstep = (t >> 6) & 3;
    const int ntile = t >> 8;
    const int n = ntile * 16 + (L & 15);
    const int kbase = kstep * 32 + (L >> 4) * 8;

    f16x8 h1 = {0,0,0,0,0,0,0,0};
    if (n < 252) {
        const int c = n >> 1, part = n & 1;
        const int s = c >> 1, kidx = c & 1;
        int l = 0, nn = 0;
        for (int i = 0; i < s; ++i) dfs_next(l, nn);

        // Leaf-only per-thread constant: cosaz for this beam column.
        const double step = (-2.0 + 5e-13) / 63.0;   // (cos(pi-1e-6)-1)/63
        const double cosaz = 1.0 + (double)(2 * nn + kidx) * step;

#pragma unroll
        for (int j = 0; j < 8; ++j) {
            const int k = kbase + j;
            const int a = k & 63;       // antenna
            const int hi = k >> 6;      // 0: real-part rows, 1: imag-part rows
            float wr, wi;
            if (l < 5) {
                const float* th = (l == 0) ? t0 : (l == 1) ? t1 : (l == 2) ? t2
                                 : (l == 3) ? t3 : t4;
                float theta = th[(nn * N_ANT + a) * 2 + kidx];
                float sn, cs;
                sincosf(theta, &sn, &cs);
                wr = cs * 0.125f; wi = sn * 0.125f;
            } else {
                // W = exp(i*pi*a*cosaz)/8. Reduce phase/(2pi) in f64 (FMA
                // only), then f32 sincos of 2*pi*frac — no f64 libm.
                double tph = (double)a * cosaz * 0.5;
                tph -= floor(tph);                    // [0,1)
                const float ang = (float)tph * 6.283185307179586f;
                float sn, cs;
                sincosf(ang, &sn, &cs);
                wr = cs * 0.125f;
                wi = sn * 0.125f;
            }
            float v = (part == 0) ? (hi == 0 ? wr : -wi)
                                  : (hi == 0 ? wi :  wr);
            h1[j] = (_Float16)v;    // round-to-nearest fp16
        }
    }
    *(f16x8*)(B1p + (size_t)t * 8) = h1;
}

// 8 waves x 2 m-tiles each: halves the per-CU LDS b-fragment read traffic
// (the measured bottleneck) vs 16 waves x 1 m-tile; b-fragments are shared
// across both tiles' MFMAs. No min-waves hint (r10: forcing 8/EU spilled).
__global__ __launch_bounds__(TPB) void beam_mfma(const float* __restrict__ x,
                                                 const _Float16* __restrict__ W1p,
                                                 float* __restrict__ out) {
    // x slice (32 elems x 128) as fp16, frag-swizzled, double-buffered (16 KB).
    __shared__ _Float16 xb[2][4096];
    // softmax pairs in FP16, ELEM-major [32 elems][PSTRH], dbuf (16.1 KB).
    __shared__ _Float16 pb[2][EPR * PSTRH];

    const int tid = threadIdx.x;
    const int w   = tid >> 6;     // wave 0..7 = m-tiles 2w,2w+1 (units 8w..8w+7)
    const int L   = tid & 63;
    const int q   = L >> 4;
    const int e15 = L & 15;

    // ---- W fragments (A-operand) for m-tiles 2w+t, single fp16 image.
    f16x8 w1f[2][4];
#pragma unroll
    for (int t = 0; t < 2; ++t)
#pragma unroll
        for (int ks = 0; ks < 4; ++ks)
            w1f[t][ks] =
                *(const f16x8*)(W1p + (size_t)(((2 * w + t) * 4 + ks) * 64 + L) * 8);

    // ---- Per-lane DFS metadata: lane u == DFS unit u in the tree phase.
    int myl = -1, myn = 0;
    {
        int cl = 0, cn = 0;
        for (int s = 0; s < NSTEPS; ++s) {
            if (s == L) { myl = cl; myn = cn; }
            dfs_next(cl, cn);
        }
    }
    // Leaf lane: DFS indices of its 5 internal ancestors + branch sides.
    const int sd0 = (myn >> 4) & 1, sd1 = (myn >> 3) & 1, sd2 = (myn >> 2) & 1,
              sd3 = (myn >> 1) & 1, sd4 = myn & 1;
    const int a0 = 0;
    const int a1 = a0 + 1 + sd0 * 31;   // subtree sizes 31,15,7,3
    const int a2 = a1 + 1 + sd1 * 15;
    const int a3 = a2 + 1 + sd2 * 7;
    const int a4 = a3 + 1 + sd3 * 3;

    // ---- Staging decode: thread stages ONE fragment slot (8 floats) of
    // the round's 32x128 x slice. er fastest -> conflict-free LDS writes.
    const int s_er = tid & 31;
    const int s_rt = tid >> 5;            // 0..15 = ks*4 + q
    const int s_ks = s_rt >> 2;
    const int s_q  = s_rt & 3;
    const int s_goff = s_er * 128 + s_ks * 32 + s_q * 8;    // floats
    const int s_loff = (s_rt * 32 + s_er) * 8;              // halves

    const long base = (long)blockIdx.x * (EPR * ROUNDS);

    // Tree cascade for round rr using buffer bb (wave-private, 4 elems).
    auto tree_pass = [&](int bb, int rr) {
#pragma unroll
        for (int pass = 0; pass < 4; ++pass) {
            const int er = 4 * w + pass;
            const _Float16* prow = &pb[bb][er * PSTRH];
            if (myl == 5) {
                f16x2 ownh = *(const f16x2*)(prow + 2 * L);
                f16x2 q0 = *(const f16x2*)(prow + 2 * a0);
                f16x2 q1 = *(const f16x2*)(prow + 2 * a1);
                f16x2 q2 = *(const f16x2*)(prow + 2 * a2);
                f16x2 q3 = *(const f16x2*)(prow + 2 * a3);
                f16x2 q4 = *(const f16x2*)(prow + 2 * a4);
                float P = (float)(sd0 ? q0.y : q0.x) * (float)(sd1 ? q1.y : q1.x)
                        * (float)(sd2 ? q2.y : q2.x) * (float)(sd3 ? q3.y : q3.x)
                        * (float)(sd4 ? q4.y : q4.x);
                *(v2f*)(out + (base + (long)rr * EPR + er) * 64 + 2 * myn) =
                    (v2f){P * (float)ownh.x, P * (float)ownh.y};
            }
        }
    };

    // Prologue: stage slice 0; pre-load slice 1 into registers.
    {
        float4 va = *(const float4*)(x + base * 128 + s_goff);
        float4 vb = *(const float4*)(x + base * 128 + s_goff + 4);
        f16x8 hv = {(_Float16)va.x, (_Float16)va.y, (_Float16)va.z, (_Float16)va.w,
                    (_Float16)vb.x, (_Float16)vb.y, (_Float16)vb.z, (_Float16)vb.w};
        *(f16x8*)(&xb[0][s_loff]) = hv;
    }
    float4 nva = {0.f,0.f,0.f,0.f}, nvb = {0.f,0.f,0.f,0.f};
    if (ROUNDS > 1) {
        nva = *(const float4*)(x + (base + EPR) * 128 + s_goff);
        nvb = *(const float4*)(x + (base + EPR) * 128 + s_goff + 4);
    }
    BAR_LGKM();

#pragma unroll 1
    for (int r = 0; r < ROUNDS; ++r) {
        const int cur = r & 1;
        // Issue the r+2 load now: a full round between issue and use.
        float4 nv2a = {0.f,0.f,0.f,0.f}, nv2b = {0.f,0.f,0.f,0.f};
        if (r + 2 < ROUNDS) {
            nv2a = *(const float4*)(x + (base + (long)(r + 2) * EPR) * 128 + s_goff);
            nv2b = *(const float4*)(x + (base + (long)(r + 2) * EPR) * 128 + s_goff + 4);
        }

        // ---- MFMA: 4 chains (2 elem-groups x 2 m-tiles); b-frags read once.
        f32x4 acc00 = {0,0,0,0}, acc01 = {0,0,0,0};   // tile 0: groups 0,1
        f32x4 acc10 = {0,0,0,0}, acc11 = {0,0,0,0};   // tile 1: groups 0,1
#pragma unroll
        for (int ks = 0; ks < 4; ++ks) {
            const _Float16* xc = &xb[cur][(size_t)((ks * 4 + q) * 32) * 8];
            f16x8 b0 = *(const f16x8*)(xc + e15 * 8);
            f16x8 b1 = *(const f16x8*)(xc + (16 + e15) * 8);
            acc00 = __builtin_amdgcn_mfma_f32_16x16x32_f16(w1f[0][ks], b0, acc00, 0, 0, 0);
            acc01 = __builtin_amdgcn_mfma_f32_16x16x32_f16(w1f[0][ks], b1, acc01, 0, 0, 0);
            acc10 = __builtin_amdgcn_mfma_f32_16x16x32_f16(w1f[1][ks], b0, acc10, 0, 0, 0);
            acc11 = __builtin_amdgcn_mfma_f32_16x16x32_f16(w1f[1][ks], b1, acc11, 0, 0, 0);
        }

        // ---- Tree for the PREVIOUS round, hidden under the MFMA phase
        // (reads pb[cur^1]; softmax below writes pb[cur] — disjoint).
        if (r > 0) tree_pass(cur ^ 1, r - 1);

        // ---- Lane-local softmax: lane holds (re0,im0,re1,im1) of units
        // u = 4*(2w+t)+q for elem er = g*16+e15. fp16 pair stores.
#pragma unroll
        for (int t = 0; t < 2; ++t) {
            const int u = (2 * w + t) * 4 + q;
#pragma unroll
            for (int g = 0; g < 2; ++g) {
                f32x4 a = t ? (g ? acc11 : acc10) : (g ? acc01 : acc00);
                float g0 = fmaf(a.x, a.x, a.y * a.y);
                float g1 = fmaf(a.z, a.z, a.w * a.w);
                float m  = fmaxf(g0, g1);
                float e0 = __expf(g0 - m);
                float e1 = __expf(g1 - m);
                float inv = fast_rcp(e0 + e1);
                if (u < NSTEPS)   // u==63 = zero-padded cols, must not write
                    *(f16x2*)(&pb[cur][(g * 16 + e15) * PSTRH + 2 * u]) =
                        (f16x2){(_Float16)(e0 * inv), (_Float16)(e1 * inv)};
            }
        }

        // ---- Stage slice r+1 (loaded a full round ago -> latency hidden).
        if (r + 1 < ROUNDS) {
            f16x8 hv = {(_Float16)nva.x, (_Float16)nva.y, (_Float16)nva.z, (_Float16)nva.w,
                        (_Float16)nvb.x, (_Float16)nvb.y, (_Float16)nvb.z, (_Float16)nvb.w};
            *(f16x8*)(&xb[cur ^ 1][s_loff]) = hv;
        }
        nva = nv2a; nvb = nv2b;

        BAR_LGKM();   // LDS visibility only; no vmcnt drain of stores/prefetch
    }

    // Epilogue: tree for the final round.
    tree_pass((ROUNDS - 1) & 1, ROUNDS - 1);
}

extern "C" void kernel_launch(void* const* d_in, const int* in_sizes, int n_in,
                              void* d_out, int out_size, void* d_ws, size_t ws_size,
                              hipStream_t stream) {
    const float* x  = (const float*)d_in[0];
    const float* t0 = (const float*)d_in[1];
    const float* t1 = (const float*)d_in[2];
    const float* t2 = (const float*)d_in[3];
    const float* t3 = (const float*)d_in[4];
    const float* t4 = (const float*)d_in[5];
    _Float16* W1p = (_Float16*)d_ws;                      // 64 KB

    fill_B<<<dim3(16), dim3(256), 0, stream>>>(t0, t1, t2, t3, t4, W1p);
    beam_mfma<<<dim3(NBLK), dim3(TPB), 0, stream>>>(x, W1p, (float*)d_out);
}